// Round 4
// baseline (395.762 us; speedup 1.0000x reference)
//
#include <hip/hip_runtime.h>

// ColBERT MaxSim scoring: scores[n] = sum_q max_m( mask ? <Q[b,q,:], D[n,m,:]> : 0 )
// B=64, LQ=32, LD=512, Dh=128, NUM_DOCS=16, N=1024. fp32 inputs, fp32 out.

typedef __attribute__((ext_vector_type(8))) short short8;   // 8 bf16 (4 VGPRs) MFMA A/B frag
typedef __attribute__((ext_vector_type(4))) float f32x4;    // MFMA C/D frag
typedef __attribute__((ext_vector_type(4))) float float4v;

static constexpr int LQ = 32;
static constexpr int LD = 512;
static constexpr int DH = 128;

__device__ __forceinline__ unsigned short f2bf(float f) {
    // round-to-nearest-even fp32 -> bf16 (inputs are finite; no NaN path needed)
    unsigned u = __builtin_bit_cast(unsigned, f);
    u += 0x7FFFu + ((u >> 16) & 1u);
    return (unsigned short)(u >> 16);
}

__device__ __forceinline__ short8 cvt8(float4v a, float4v b) {
    short8 f;
    f[0] = (short)f2bf(a[0]); f[1] = (short)f2bf(a[1]);
    f[2] = (short)f2bf(a[2]); f[3] = (short)f2bf(a[3]);
    f[4] = (short)f2bf(b[0]); f[5] = (short)f2bf(b[1]);
    f[6] = (short)f2bf(b[2]); f[7] = (short)f2bf(b[3]);
    return f;
}

// Detect whether bool masks were uploaded as 1-byte bools (flag=1) or int32 (flag=0).
// int32 layout of {0,1} values has every byte at offset%4!=0 equal to 0.
__global__ void detect_mask_layout(const unsigned char* __restrict__ dm, int* __restrict__ flag) {
    const int t = threadIdx.x;
    int found = 0;
    for (int i = t; i < 16384; i += 256)
        if ((i & 3) && dm[i]) found = 1;
    unsigned long long b = __ballot(found);
    __shared__ int s[4];
    if ((t & 63) == 0) s[t >> 6] = (b != 0ULL) ? 1 : 0;
    __syncthreads();
    if (t == 0) flag[0] = s[0] | s[1] | s[2] | s[3];
}

__global__ __launch_bounds__(256, 4)
void colbert_score_kernel(const float* __restrict__ q_emb,
                          const float* __restrict__ d_emb,
                          const unsigned char* __restrict__ qmask,
                          const unsigned char* __restrict__ dmask,
                          const int* __restrict__ flag,
                          float* __restrict__ out,
                          int ndocs) {
    const int n    = blockIdx.x;
    const int b    = n / ndocs;
    const int t    = threadIdx.x;
    const int wave = t >> 6;
    const int l    = t & 63;
    const int lrow = l & 15;   // fragment row (A) / col (B)
    const int lk   = l >> 4;   // k-group 0..3
    const bool bytemask = (flag[0] != 0);   // grid-uniform

    // ---- Q fragments: 2 q-tiles x 4 k-steps, held in registers for the whole block
    short8 qf[2][4];
    {
        const float* qb = q_emb + (size_t)b * LQ * DH;
        #pragma unroll
        for (int qt = 0; qt < 2; ++qt) {
            const float* qrow = qb + (size_t)(qt * 16 + lrow) * DH + lk * 8;
            #pragma unroll
            for (int ks = 0; ks < 4; ++ks) {
                float4v a = *(const float4v*)(qrow + ks * 32);
                float4v c = *(const float4v*)(qrow + ks * 32 + 4);
                qf[qt][ks] = cvt8(a, c);
            }
        }
    }

    float rmax[2][4];
    #pragma unroll
    for (int qt = 0; qt < 2; ++qt)
        #pragma unroll
        for (int r = 0; r < 4; ++r) rmax[qt][r] = -3.402823466e38f;

    const float*         dn  = d_emb + (size_t)n * LD * DH;
    const unsigned char* dmb = dmask + (size_t)n * LD;
    const int*           dmi = (const int*)dmask + (size_t)n * LD;

    // ---- main loop: each wave owns m-tiles {wave, wave+4, ...} (8 tiles of 16 doc tokens)
    for (int mt = wave; mt < LD / 16; mt += 4) {
        const int row = mt * 16 + lrow;
        const float* dp = dn + (size_t)row * DH + lk * 8;

        float4v v[8];
        #pragma unroll
        for (int ks = 0; ks < 4; ++ks) {
            v[2 * ks]     = *(const float4v*)(dp + ks * 32);
            v[2 * ks + 1] = *(const float4v*)(dp + ks * 32 + 4);
        }
        // uniform branch: never touch the wrong-layout address (OOB safety)
        int mv;
        if (bytemask) mv = (int)dmb[row];
        else          mv = dmi[row];

        short8 bf[4];
        #pragma unroll
        for (int ks = 0; ks < 4; ++ks) bf[ks] = cvt8(v[2 * ks], v[2 * ks + 1]);

        f32x4 acc0 = {0.f, 0.f, 0.f, 0.f};
        f32x4 acc1 = {0.f, 0.f, 0.f, 0.f};
        #pragma unroll
        for (int ks = 0; ks < 4; ++ks) {
            acc0 = __builtin_amdgcn_mfma_f32_16x16x32_bf16(qf[0][ks], bf[ks], acc0, 0, 0, 0);
            acc1 = __builtin_amdgcn_mfma_f32_16x16x32_bf16(qf[1][ks], bf[ks], acc1, 0, 0, 0);
        }
        // lane l, reg r holds sim[q = (l>>4)*4 + r + 16*qt][m = mt*16 + (l&15)]  (m89 C/D layout)
        #pragma unroll
        for (int r = 0; r < 4; ++r) {
            float v0 = mv ? acc0[r] : 0.0f;
            float v1 = mv ? acc1[r] : 0.0f;
            rmax[0][r] = fmaxf(rmax[0][r], v0);
            rmax[1][r] = fmaxf(rmax[1][r], v1);
        }
    }

    // ---- max over the 16 m-columns living in lanes (xor over low 4 lane bits)
    #pragma unroll
    for (int off = 1; off <= 8; off <<= 1) {
        #pragma unroll
        for (int qt = 0; qt < 2; ++qt)
            #pragma unroll
            for (int r = 0; r < 4; ++r)
                rmax[qt][r] = fmaxf(rmax[qt][r], __shfl_xor(rmax[qt][r], off, 64));
    }

    __shared__ float smax[4][32];
    if (lrow == 0) {
        #pragma unroll
        for (int qt = 0; qt < 2; ++qt)
            #pragma unroll
            for (int r = 0; r < 4; ++r)
                smax[wave][qt * 16 + lk * 4 + r] = rmax[qt][r];
    }
    __syncthreads();

    if (t < 32) {
        float m4 = fmaxf(fmaxf(smax[0][t], smax[1][t]), fmaxf(smax[2][t], smax[3][t]));
        const int qidx = b * LQ + t;
        int qmv;
        if (bytemask) qmv = (int)qmask[qidx];
        else          qmv = ((const int*)qmask)[qidx];
        float val = qmv ? m4 : 0.0f;
        #pragma unroll
        for (int off = 1; off <= 16; off <<= 1) val += __shfl_xor(val, off, 64);
        if (t == 0) out[n] = val;
    }
}

extern "C" void kernel_launch(void* const* d_in, const int* in_sizes, int n_in,
                              void* d_out, int out_size, void* d_ws, size_t ws_size,
                              hipStream_t stream) {
    const float*         q_emb = (const float*)d_in[0];
    const float*         d_emb = (const float*)d_in[1];
    const unsigned char* qmask = (const unsigned char*)d_in[2];
    const unsigned char* dmask = (const unsigned char*)d_in[3];

    const int N  = in_sizes[1] / (LD * DH);   // 1024
    const int Bq = in_sizes[0] / (LQ * DH);   // 64
    const int ndocs = N / Bq;                 // 16

    int* flag = (int*)d_ws;
    hipLaunchKernelGGL(detect_mask_layout, dim3(1), dim3(256), 0, stream, dmask, flag);
    hipLaunchKernelGGL(colbert_score_kernel, dim3(N), dim3(256), 0, stream,
                       q_emb, d_emb, qmask, dmask, flag, (float*)d_out, ndocs);
}

// Round 5
// 369.649 us; speedup vs baseline: 1.0706x; 1.0706x over previous
//
#include <hip/hip_runtime.h>
#include <hip/hip_bf16.h>

// ColBERT MaxSim scoring: scores[n] = sum_q max_m( mask ? <Q[b,q,:], D[n,m,:]> : 0 )
// B=64, LQ=32, LD=512, Dh=128, NUM_DOCS=16, N=1024. fp32 inputs, fp32 out.
//
// One block per doc n. Q tile (32x128) lives in MFMA A-fragments in registers.
// Doc tiles stream global->regs->bf16->MFMA (no LDS staging: zero reuse).
// Memory floor: 256 MB doc embeddings / 6.3 TB/s ~= 41 us.

typedef __attribute__((ext_vector_type(8))) short short8;   // 8 bf16 (4 VGPRs) MFMA A/B frag
typedef __attribute__((ext_vector_type(4))) float f32x4;    // MFMA C/D frag
typedef __attribute__((ext_vector_type(4))) float float4v;

static constexpr int LQ = 32;
static constexpr int LD = 512;
static constexpr int DH = 128;

__device__ __forceinline__ short bfbits(float f) {
    return (short)__builtin_bit_cast(unsigned short, __float2bfloat16(f));
}

__device__ __forceinline__ short8 cvt8(float4v a, float4v b) {
    short8 f;
    f[0] = bfbits(a[0]); f[1] = bfbits(a[1]); f[2] = bfbits(a[2]); f[3] = bfbits(a[3]);
    f[4] = bfbits(b[0]); f[5] = bfbits(b[1]); f[6] = bfbits(b[2]); f[7] = bfbits(b[3]);
    return f;
}

// NOTE: no min-waves arg — a forced 4 waves/EU caps VGPR at 128 and spills
// the ~140-reg hot loop to scratch (R4 post-mortem suspect).
__global__ __launch_bounds__(256)
void colbert_score_kernel(const float* __restrict__ q_emb,
                          const float* __restrict__ d_emb,
                          const unsigned char* __restrict__ qmask,
                          const unsigned char* __restrict__ dmask,
                          float* __restrict__ out,
                          int ndocs) {
    const int n    = blockIdx.x;
    const int b    = n / ndocs;
    const int t    = threadIdx.x;
    const int wave = t >> 6;
    const int l    = t & 63;
    const int lrow = l & 15;   // fragment row (A) / col (B)
    const int lk   = l >> 4;   // k-group 0..3

    // ---- in-block mask-layout detection (byte bools vs int32), first 4 KB of dmask.
    // int32 layout of {0,1}: every byte at offset%4!=0 is zero. 4096 random byte-bools
    // make a nonzero there w.p. 1-2^-3072. All blocks read the same 4 KB -> L2 broadcast.
    __shared__ int s_flag[4];
    {
        const uint4 v = ((const uint4*)dmask)[t];   // 256 thr x 16 B = 4 KB
        const unsigned hz = (v.x | v.y | v.z | v.w) & 0xFFFFFF00u;
        unsigned long long bal = __ballot(hz != 0u);
        if (l == 0) s_flag[wave] = (bal != 0ULL) ? 1 : 0;
    }
    __syncthreads();
    const bool bytemask = (s_flag[0] | s_flag[1] | s_flag[2] | s_flag[3]) != 0;

    // ---- Q fragments: 2 q-tiles x 4 k-steps, held in registers for the whole block
    short8 qf[2][4];
    {
        const float* qb = q_emb + (size_t)b * LQ * DH;
        #pragma unroll
        for (int qt = 0; qt < 2; ++qt) {
            const float* qrow = qb + (size_t)(qt * 16 + lrow) * DH + lk * 8;
            #pragma unroll
            for (int ks = 0; ks < 4; ++ks) {
                float4v a = *(const float4v*)(qrow + ks * 32);
                float4v c = *(const float4v*)(qrow + ks * 32 + 4);
                qf[qt][ks] = cvt8(a, c);
            }
        }
    }

    float rmax[2][4];
    #pragma unroll
    for (int qt = 0; qt < 2; ++qt)
        #pragma unroll
        for (int r = 0; r < 4; ++r) rmax[qt][r] = -3.402823466e38f;

    const float*         dn  = d_emb + (size_t)n * LD * DH;
    const unsigned char* dmb = dmask + (size_t)n * LD;
    const int*           dmi = (const int*)dmask + (size_t)n * LD;

    // ---- main loop: each wave owns m-tiles {wave, wave+4, ...} (8 tiles of 16 doc tokens)
    for (int mt = wave; mt < LD / 16; mt += 4) {
        const int row = mt * 16 + lrow;
        const float* dp = dn + (size_t)row * DH + lk * 8;

        float4v v[8];
        #pragma unroll
        for (int ks = 0; ks < 4; ++ks) {
            v[2 * ks]     = *(const float4v*)(dp + ks * 32);
            v[2 * ks + 1] = *(const float4v*)(dp + ks * 32 + 4);
        }
        // uniform branch: never touch the wrong-layout address (OOB safety)
        int mv;
        if (bytemask) mv = (int)dmb[row];
        else          mv = dmi[row];

        short8 bf[4];
        #pragma unroll
        for (int ks = 0; ks < 4; ++ks) bf[ks] = cvt8(v[2 * ks], v[2 * ks + 1]);

        f32x4 acc0 = {0.f, 0.f, 0.f, 0.f};
        f32x4 acc1 = {0.f, 0.f, 0.f, 0.f};
        #pragma unroll
        for (int ks = 0; ks < 4; ++ks) {
            acc0 = __builtin_amdgcn_mfma_f32_16x16x32_bf16(qf[0][ks], bf[ks], acc0, 0, 0, 0);
            acc1 = __builtin_amdgcn_mfma_f32_16x16x32_bf16(qf[1][ks], bf[ks], acc1, 0, 0, 0);
        }
        // lane l, reg r holds sim[q = (l>>4)*4 + r + 16*qt][m = mt*16 + (l&15)]  (m89 C/D layout)
        #pragma unroll
        for (int r = 0; r < 4; ++r) {
            float v0 = mv ? acc0[r] : 0.0f;
            float v1 = mv ? acc1[r] : 0.0f;
            rmax[0][r] = fmaxf(rmax[0][r], v0);
            rmax[1][r] = fmaxf(rmax[1][r], v1);
        }
    }

    // ---- max over the 16 m-columns living in lanes (xor over low 4 lane bits)
    #pragma unroll
    for (int off = 1; off <= 8; off <<= 1) {
        #pragma unroll
        for (int qt = 0; qt < 2; ++qt)
            #pragma unroll
            for (int r = 0; r < 4; ++r)
                rmax[qt][r] = fmaxf(rmax[qt][r], __shfl_xor(rmax[qt][r], off, 64));
    }

    __shared__ float smax[4][32];
    if (lrow == 0) {
        #pragma unroll
        for (int qt = 0; qt < 2; ++qt)
            #pragma unroll
            for (int r = 0; r < 4; ++r)
                smax[wave][qt * 16 + lk * 4 + r] = rmax[qt][r];
    }
    __syncthreads();

    if (t < 32) {
        float m4 = fmaxf(fmaxf(smax[0][t], smax[1][t]), fmaxf(smax[2][t], smax[3][t]));
        const int qidx = b * LQ + t;
        int qmv;
        if (bytemask) qmv = (int)qmask[qidx];
        else          qmv = ((const int*)qmask)[qidx];
        float val = qmv ? m4 : 0.0f;
        #pragma unroll
        for (int off = 1; off <= 16; off <<= 1) val += __shfl_xor(val, off, 64);
        if (t == 0) out[n] = val;
    }
}

extern "C" void kernel_launch(void* const* d_in, const int* in_sizes, int n_in,
                              void* d_out, int out_size, void* d_ws, size_t ws_size,
                              hipStream_t stream) {
    const float*         q_emb = (const float*)d_in[0];
    const float*         d_emb = (const float*)d_in[1];
    const unsigned char* qmask = (const unsigned char*)d_in[2];
    const unsigned char* dmask = (const unsigned char*)d_in[3];

    const int N  = in_sizes[1] / (LD * DH);   // 1024
    const int Bq = in_sizes[0] / (LQ * DH);   // 64
    const int ndocs = N / Bq;                 // 16

    hipLaunchKernelGGL(colbert_score_kernel, dim3(N), dim3(256), 0, stream,
                       q_emb, d_emb, qmask, dmask, (float*)d_out, ndocs);
}

// Round 6
// 339.286 us; speedup vs baseline: 1.1665x; 1.0895x over previous
//
#include <hip/hip_runtime.h>
#include <hip/hip_bf16.h>

// ColBERT MaxSim scoring: scores[n] = sum_q max_m( mask ? <Q[b,q,:], D[n,m,:]> : 0 )
// B=64, LQ=32, LD=512, Dh=128, NUM_DOCS=16, N=1024. fp32 inputs, fp32 out.
//
// One block per doc n. Q tile (32x128) in MFMA A-fragments in registers.
// Doc rows stream global->regs->bf16->MFMA. KEY: masked doc rows (P=0.5)
// contribute 0 to the max, so their 512 B embedding rows are never fetched
// (exec-masked loads -> ~128 MB instead of 256 MB HBM traffic, floor ~21 us).
// Row masks are staged to LDS once per block so the gate costs ~nothing.

typedef __attribute__((ext_vector_type(8))) short short8;   // 8 bf16 (4 VGPRs) MFMA A/B frag
typedef __attribute__((ext_vector_type(4))) float f32x4;    // MFMA C/D frag
typedef __attribute__((ext_vector_type(4))) float float4v;

static constexpr int LQ = 32;
static constexpr int LD = 512;
static constexpr int DH = 128;

__device__ __forceinline__ short bfbits(float f) {
    return (short)__builtin_bit_cast(unsigned short, __float2bfloat16(f));
}

__device__ __forceinline__ short8 cvt8(float4v a, float4v b) {
    short8 f;
    f[0] = bfbits(a[0]); f[1] = bfbits(a[1]); f[2] = bfbits(a[2]); f[3] = bfbits(a[3]);
    f[4] = bfbits(b[0]); f[5] = bfbits(b[1]); f[6] = bfbits(b[2]); f[7] = bfbits(b[3]);
    return f;
}

__global__ __launch_bounds__(256, 4)
void colbert_score_kernel(const float* __restrict__ q_emb,
                          const float* __restrict__ d_emb,
                          const unsigned char* __restrict__ qmask,
                          const unsigned char* __restrict__ dmask,
                          float* __restrict__ out,
                          int ndocs) {
    const int n    = blockIdx.x;
    const int b    = n / ndocs;
    const int t    = threadIdx.x;
    const int wave = t >> 6;
    const int l    = t & 63;
    const int lrow = l & 15;   // fragment row (A) / col (B)
    const int lk   = l >> 4;   // k-group 0..3

    __shared__ int s_flag[4];
    __shared__ unsigned char smask[LD];   // this doc's 512 row masks, as bytes

    // ---- mask-layout detection (byte bools vs int32) on first 4 KB of dmask.
    // int32 layout of {0,1}: every byte at offset%4!=0 is zero. All blocks read
    // the same 4 KB -> L2/L3 broadcast, negligible HBM.
    {
        const uint4 v = ((const uint4*)dmask)[t];   // 256 thr x 16 B = 4 KB
        const unsigned hz = (v.x | v.y | v.z | v.w) & 0xFFFFFF00u;
        unsigned long long bal = __ballot(hz != 0u);
        if (l == 0) s_flag[wave] = (bal != 0ULL) ? 1 : 0;
    }
    __syncthreads();
    const bool bytemask = (s_flag[0] | s_flag[1] | s_flag[2] | s_flag[3]) != 0;

    // ---- stage this doc's row masks into LDS (normalized to 1 byte per row)
    if (bytemask) {
        if (t < LD / 16)
            ((uint4*)smask)[t] = ((const uint4*)(dmask + (size_t)n * LD))[t];
    } else {
        if (t < LD / 4) {
            const int4 m = ((const int4*)((const int*)dmask + (size_t)n * LD))[t];
            smask[4 * t + 0] = (unsigned char)(m.x != 0);
            smask[4 * t + 1] = (unsigned char)(m.y != 0);
            smask[4 * t + 2] = (unsigned char)(m.z != 0);
            smask[4 * t + 3] = (unsigned char)(m.w != 0);
        }
    }

    // ---- Q fragments: 2 q-tiles x 4 k-steps, in registers for the whole block
    // (independent of smask -> overlaps with the staging above)
    short8 qf[2][4];
    {
        const float* qb = q_emb + (size_t)b * LQ * DH;
        #pragma unroll
        for (int qt = 0; qt < 2; ++qt) {
            const float* qrow = qb + (size_t)(qt * 16 + lrow) * DH + lk * 8;
            #pragma unroll
            for (int ks = 0; ks < 4; ++ks) {
                float4v a = *(const float4v*)(qrow + ks * 32);
                float4v c = *(const float4v*)(qrow + ks * 32 + 4);
                qf[qt][ks] = cvt8(a, c);
            }
        }
    }

    __syncthreads();   // smask ready

    float rmax[2][4];
    #pragma unroll
    for (int qt = 0; qt < 2; ++qt)
        #pragma unroll
        for (int r = 0; r < 4; ++r) rmax[qt][r] = -3.402823466e38f;

    const float* dn = d_emb + (size_t)n * LD * DH;

    // ---- main loop: each wave owns m-tiles {wave, wave+4, ...} (8 tiles of 16 rows)
    for (int mt = wave; mt < LD / 16; mt += 4) {
        const int row = mt * 16 + lrow;
        const int mv  = (int)smask[row];   // LDS, same-dword broadcast per 4 lanes

        short8 bf[4] = {};                 // masked rows: B-fragment = 0
        if (mv) {                          // exec-masked: masked rows fetch NOTHING
            const float* dp = dn + (size_t)row * DH + lk * 8;
            #pragma unroll
            for (int ks = 0; ks < 4; ++ks) {
                float4v a = *(const float4v*)(dp + ks * 32);
                float4v c = *(const float4v*)(dp + ks * 32 + 4);
                bf[ks] = cvt8(a, c);
            }
        }

        f32x4 acc0 = {0.f, 0.f, 0.f, 0.f};
        f32x4 acc1 = {0.f, 0.f, 0.f, 0.f};
        #pragma unroll
        for (int ks = 0; ks < 4; ++ks) {
            acc0 = __builtin_amdgcn_mfma_f32_16x16x32_bf16(qf[0][ks], bf[ks], acc0, 0, 0, 0);
            acc1 = __builtin_amdgcn_mfma_f32_16x16x32_bf16(qf[1][ks], bf[ks], acc1, 0, 0, 0);
        }
        // lane l, reg r holds sim[q = (l>>4)*4 + r + 16*qt][m = mt*16 + (l&15)]  (m89 C/D layout)
        // masked column -> acc is exactly 0 (bf=0), matching reference where(mask, sim, 0)
        #pragma unroll
        for (int r = 0; r < 4; ++r) {
            rmax[0][r] = fmaxf(rmax[0][r], mv ? acc0[r] : 0.0f);
            rmax[1][r] = fmaxf(rmax[1][r], mv ? acc1[r] : 0.0f);
        }
    }

    // ---- max over the 16 m-columns living in lanes (xor over low 4 lane bits)
    #pragma unroll
    for (int off = 1; off <= 8; off <<= 1) {
        #pragma unroll
        for (int qt = 0; qt < 2; ++qt)
            #pragma unroll
            for (int r = 0; r < 4; ++r)
                rmax[qt][r] = fmaxf(rmax[qt][r], __shfl_xor(rmax[qt][r], off, 64));
    }

    __shared__ float smax[4][32];
    if (lrow == 0) {
        #pragma unroll
        for (int qt = 0; qt < 2; ++qt)
            #pragma unroll
            for (int r = 0; r < 4; ++r)
                smax[wave][qt * 16 + lk * 4 + r] = rmax[qt][r];
    }
    __syncthreads();

    if (t < 32) {
        float m4 = fmaxf(fmaxf(smax[0][t], smax[1][t]), fmaxf(smax[2][t], smax[3][t]));
        const int qidx = b * LQ + t;
        int qmv;
        if (bytemask) qmv = (int)qmask[qidx];
        else          qmv = ((const int*)qmask)[qidx];
        float val = qmv ? m4 : 0.0f;
        #pragma unroll
        for (int off = 1; off <= 16; off <<= 1) val += __shfl_xor(val, off, 64);
        if (t == 0) out[n] = val;
    }
}

extern "C" void kernel_launch(void* const* d_in, const int* in_sizes, int n_in,
                              void* d_out, int out_size, void* d_ws, size_t ws_size,
                              hipStream_t stream) {
    const float*         q_emb = (const float*)d_in[0];
    const float*         d_emb = (const float*)d_in[1];
    const unsigned char* qmask = (const unsigned char*)d_in[2];
    const unsigned char* dmask = (const unsigned char*)d_in[3];

    const int N  = in_sizes[1] / (LD * DH);   // 1024
    const int Bq = in_sizes[0] / (LQ * DH);   // 64
    const int ndocs = N / Bq;                 // 16

    hipLaunchKernelGGL(colbert_score_kernel, dim3(N), dim3(256), 0, stream,
                       q_emb, d_emb, qmask, dmask, (float*)d_out, ndocs);
}